// Round 2
// baseline (221.639 us; speedup 1.0000x reference)
//
#include <hip/hip_runtime.h>

// SNN conv layer: 3x3x16->64 conv (SAME) on 512x512 NHWC + old_potentials,
// threshold 1.0 -> (spikes, reset potentials).
// R5: bf16 implicit-GEMM via mfma_f32_16x16x32_bf16 (93.5us kernel).
// R6: A=weights/co, B=pixels operand swap -> vectorized dwordx4 epilogue
//   (~78us inferred; still ~2x the ~35-40us write-BW roofline, latency-bound).
// R7: attack exposed latency + occupancy:
//   (a) oldp prefetch issued at kernel ENTRY (addresses need no staging) so
//       HBM latency hides under staging+MFMA instead of sitting at the tail;
//   (b) TY 8->4 (grid 2048 blocks), acc[2][4]+oldv[2][4] => ~110 VGPR,
//       __launch_bounds__(256,4): 16 waves/CU (was 12) + smoother tail;
//   (c) weights pre-packed to bf16 [n][152] in d_ws by a tiny one-off kernel;
//       hot kernel stages s_w as a vector copy (was 36 scalar L2 loads +
//       36 pack2bf per thread per block);
//   (d) non-temporal stores for the two pure-streaming outputs.

#define H 512
#define W 512
#define CI 16
#define CO 64
#define TX 32
#define TY 4
#define XT 34          // staged x extent (TX + halo)
#define YT 6           // staged y extent (TY + halo)
#define PIX_US 24      // ushorts per pixel slot (16 used; 48B stride -> 2-way banks)
#define KS 152         // s_w k-stride in elements (304B -> 12-bank stride)
#define SW_CHUNKS ((CO * KS * 2) / 16)   // 1216 x 16B chunks in s_w

typedef float v4f __attribute__((ext_vector_type(4)));
typedef float f32x4 __attribute__((ext_vector_type(4)));
typedef short short8 __attribute__((ext_vector_type(8)));
typedef unsigned int uint4v __attribute__((ext_vector_type(4)));

__device__ __forceinline__ unsigned int pack2bf(float f0, float f1) {
    // round-to-nearest-even bf16 truncation of two floats, packed
    unsigned u0 = __builtin_bit_cast(unsigned, f0);
    unsigned u1 = __builtin_bit_cast(unsigned, f1);
    u0 = (u0 + 0x7FFFu + ((u0 >> 16) & 1u)) >> 16;
    u1 = (u1 + 0x7FFFu + ((u1 >> 16) & 1u)) >> 16;
    return u0 | (u1 << 16);
}

// ---- one-off: pack w (3,3,16,64) f32 -> ws bf16 [n=64][k=KS] (zero tail)
__global__ void snn_pack_w(const float* __restrict__ w,
                           unsigned int* __restrict__ wsu)
{
    const int tid = threadIdx.x;
    const int n  = tid & 63;
    const int kq = tid >> 6;                 // 0..3, 36 k-values each
    #pragma unroll
    for (int kk = 0; kk < 18; ++kk) {
        const int k = kq * 36 + kk * 2;
        const float f0 = w[k * CO + n];
        const float f1 = w[(k + 1) * CO + n];
        wsu[(n * KS + k) >> 1] = pack2bf(f0, f1);
    }
    if (kq == 3) {                           // zero k = 144..151
        #pragma unroll
        for (int i = 0; i < 4; ++i)
            wsu[((n * KS + 144) >> 1) + i] = 0u;
    }
}

__global__ __launch_bounds__(256, 4)
void snn_conv_mfma(const float* __restrict__ in,
                   const uint4v* __restrict__ wsv,   // pre-packed bf16 weights
                   const float* __restrict__ oldp,
                   float* __restrict__ out_spk,
                   float* __restrict__ out_pot)
{
    __shared__ unsigned short s_in[YT * XT * PIX_US];               // 9792 B
    __shared__ alignas(16) unsigned short s_w[CO * KS];             // 19456 B

    const int tid = threadIdx.x;
    const int bx = blockIdx.x & 15;        // 16 tiles in x
    const int by = blockIdx.x >> 4;        // 128 tiles in y
    const int tx0 = bx * TX, ty0 = by * TY;

    const int lane = tid & 63;
    const int wv   = tid >> 6;       // wave 0..3 -> output row ty0+wv
    const int r    = lane & 15;      // pixel-within-16 (B/D) / co-within-16 (A)
    const int quad = lane >> 4;      // 0..3
    const int half = quad & 1;       // ci-half for pixel fragment
    const int tsel = quad >> 1;      // tap parity within K-step

    // ---- phase 0: issue ALL oldp loads first (no staging dependency) so
    // their HBM latency overlaps the staging + MFMA below.
    f32x4 oldv[2][4];
    int ebase[2];
    #pragma unroll
    for (int mt = 0; mt < 2; ++mt) {
        const int gy = ty0 + wv;
        const int gx = tx0 + mt * 16 + r;
        ebase[mt] = (gy * W + gx) * CO + quad * 4;
        #pragma unroll
        for (int nt = 0; nt < 4; ++nt)
            oldv[mt][nt] = *(const f32x4*)(oldp + ebase[mt] + nt * 16);
    }

    // ---- stage weights: straight vector copy of pre-packed bf16
    {
        uint4v* dst = (uint4v*)s_w;
        #pragma unroll
        for (int i = 0; i < 5; ++i) {
            const int idx = tid + i * 256;
            if (idx < SW_CHUNKS) dst[idx] = wsv[idx];
        }
    }

    // ---- stage input tile bf16, zero halo (YT*XT = 204 slots)
    if (tid < YT * XT) {
        const int ly = tid / XT, lx = tid - ly * XT;
        const int gy = ty0 + ly - 1, gx = tx0 + lx - 1;
        uint4v pk0, pk1;
        if ((unsigned)gy < H && (unsigned)gx < W) {
            const v4f* p = (const v4f*)(in + (gy * W + gx) * CI);
            v4f a = p[0], b = p[1], c = p[2], d = p[3];
            pk0 = (uint4v){pack2bf(a.x, a.y), pack2bf(a.z, a.w),
                           pack2bf(b.x, b.y), pack2bf(b.z, b.w)};
            pk1 = (uint4v){pack2bf(c.x, c.y), pack2bf(c.z, c.w),
                           pack2bf(d.x, d.y), pack2bf(d.z, d.w)};
        } else {
            pk0 = (uint4v)0u;
            pk1 = (uint4v)0u;
        }
        uint4v* dst = (uint4v*)&s_in[tid * PIX_US];   // 48B slot, 16B-aligned
        dst[0] = pk0;
        dst[1] = pk1;
    }
    __syncthreads();

    // ---- wave-level implicit GEMM: wave = 1 row x 32 px (2 N-tiles), 64 co
    f32x4 acc[2][4] = {};            // [mt=pixel tile][nt=co tile]

    int abase[2];
    #pragma unroll
    for (int mt = 0; mt < 2; ++mt)
        abase[mt] = (wv * XT + mt * 16 + r) * PIX_US + half * 8;

    const short8 zero8 = {0, 0, 0, 0, 0, 0, 0, 0};

    #pragma unroll
    for (int ks5 = 0; ks5 < 5; ++ks5) {
        const int t0 = ks5 * 2;
        const int t1 = (ks5 == 4) ? 8 : ks5 * 2 + 1;
        const int off0 = ((t0 / 3) * XT + (t0 % 3)) * PIX_US;  // compile-time
        const int off1 = ((t1 / 3) * XT + (t1 % 3)) * PIX_US;  // compile-time
        const int aoff = tsel ? off1 : off0;
        // weights: lane reads k = koff..koff+7 at row co = nt*16 + r
        const int koff = (ks5 < 4) ? (ks5 * 32 + quad * 8) : (128 + half * 8);

        short8 bf[4];
        #pragma unroll
        for (int nt = 0; nt < 4; ++nt)
            bf[nt] = *(const short8*)&s_w[(nt * 16 + r) * KS + koff];

        short8 af[2];
        #pragma unroll
        for (int mt = 0; mt < 2; ++mt) {
            short8 a = *(const short8*)&s_in[abase[mt] + aoff];
            if (ks5 == 4) a = (quad >= 2) ? zero8 : a;   // zero pad k=144..159
            af[mt] = a;
        }

        // A = weights (M=co), B = pixels (N=pixel); padded k zeroed on B side.
        #pragma unroll
        for (int mt = 0; mt < 2; ++mt)
            #pragma unroll
            for (int nt = 0; nt < 4; ++nt)
                acc[mt][nt] = __builtin_amdgcn_mfma_f32_16x16x32_bf16(
                    bf[nt], af[mt], acc[mt][nt], 0, 0, 0);
    }

    // ---- epilogue: D col=lane&15 (pixel), row=quad*4+reg (co-within-16).
    // oldv already in registers; pure add + threshold + streaming stores.
    #pragma unroll
    for (int mt = 0; mt < 2; ++mt) {
        #pragma unroll
        for (int nt = 0; nt < 4; ++nt) {
            const int idx = ebase[mt] + nt * 16;
            f32x4 np = acc[mt][nt] + oldv[mt][nt];
            f32x4 spk, pot;
            #pragma unroll
            for (int j = 0; j < 4; ++j) {
                const bool s = np[j] >= 1.0f;
                spk[j] = s ? 1.0f : 0.0f;
                pot[j] = s ? 0.0f : np[j];
            }
            __builtin_nontemporal_store(spk, (f32x4*)(out_spk + idx));
            __builtin_nontemporal_store(pot, (f32x4*)(out_pot + idx));
        }
    }
}

extern "C" void kernel_launch(void* const* d_in, const int* in_sizes, int n_in,
                              void* d_out, int out_size, void* d_ws, size_t ws_size,
                              hipStream_t stream) {
    const float* in   = (const float*)d_in[0];     // (1,512,512,16)
    const float* w    = (const float*)d_in[1];     // (3,3,16,64)
    const float* oldp = (const float*)d_in[2];     // (1,512,512,64)
    float* out_spk = (float*)d_out;
    float* out_pot = out_spk + (size_t)H * W * CO;

    snn_pack_w<<<1, 256, 0, stream>>>(w, (unsigned int*)d_ws);

    const int grid = (W / TX) * (H / TY);          // 2048 blocks x 256 thr
    snn_conv_mfma<<<grid, 256, 0, stream>>>(in, (const uint4v*)d_ws, oldp,
                                            out_spk, out_pot);
}

// Round 3
// 215.362 us; speedup vs baseline: 1.0291x; 1.0291x over previous
//
#include <hip/hip_runtime.h>

// SNN conv layer: 3x3x16->64 conv (SAME) on 512x512 NHWC + old_potentials,
// threshold 1.0 -> (spikes, reset potentials).
// R5: bf16 implicit-GEMM via mfma_f32_16x16x32_bf16 (93.5us kernel).
// R6: A=weights/co, B=pixels swap -> dwordx4 epilogue (~78us).
// R7: oldp entry-prefetch + TY=4 + pre-packed weights + NT stores (~81us,
//   NEUTRAL): __syncthreads drains vmcnt(0) so the prefetch died at the
//   staging barrier; single-generation blocks in lockstep -> bursty memory
//   use, 2.8 TB/s vs fillBuffer's 6.7. NT stores +36MB write traffic.
// R8: persistent pipelined blocks for CONTINUOUS memory issue:
//   - grid 512 (2 blocks/CU co-resident), 4 y-consecutive tiles per block;
//   - weights staged to LDS once per block (amortized 4x);
//   - s_in double-buffered; input+oldp loads for tile t+2 issued during
//     compute of tile t; loads stay in flight ACROSS barriers via raw
//     __builtin_amdgcn_s_barrier() + lgkmcnt(0) (no vmcnt drain);
//   - compiler's counted vmcnt handles per-dep waits (loads issued in
//     consumption order: input first, oldp second);
//   - plain stores (NT reverted).

#define H 512
#define W 512
#define CI 16
#define CO 64
#define TX 32
#define TY 4
#define XT 34          // staged x extent (TX + halo)
#define YT 6           // staged y extent (TY + halo)
#define PIX_US 24      // ushorts per pixel slot (16 used; 48B stride -> 2-way banks)
#define KS 152         // s_w k-stride in elements (304B -> 12-bank stride)
#define SW_CHUNKS ((CO * KS * 2) / 16)   // 1216 x 16B chunks in s_w
#define NTILES 4       // y-consecutive tiles per block

typedef float v4f __attribute__((ext_vector_type(4)));
typedef float f32x4 __attribute__((ext_vector_type(4)));
typedef short short8 __attribute__((ext_vector_type(8)));
typedef unsigned int uint4v __attribute__((ext_vector_type(4)));

__device__ __forceinline__ unsigned int pack2bf(float f0, float f1) {
    // round-to-nearest-even bf16 truncation of two floats, packed
    unsigned u0 = __builtin_bit_cast(unsigned, f0);
    unsigned u1 = __builtin_bit_cast(unsigned, f1);
    u0 = (u0 + 0x7FFFu + ((u0 >> 16) & 1u)) >> 16;
    u1 = (u1 + 0x7FFFu + ((u1 >> 16) & 1u)) >> 16;
    return u0 | (u1 << 16);
}

// ---- one-off: pack w (3,3,16,64) f32 -> ws bf16 [n=64][k=KS] (zero tail)
__global__ void snn_pack_w(const float* __restrict__ w,
                           unsigned int* __restrict__ wsu)
{
    const int tid = threadIdx.x;
    const int n  = tid & 63;
    const int kq = tid >> 6;                 // 0..3, 36 k-values each
    #pragma unroll
    for (int kk = 0; kk < 18; ++kk) {
        const int k = kq * 36 + kk * 2;
        const float f0 = w[k * CO + n];
        const float f1 = w[(k + 1) * CO + n];
        wsu[(n * KS + k) >> 1] = pack2bf(f0, f1);
    }
    if (kq == 3) {                           // zero k = 144..151
        #pragma unroll
        for (int i = 0; i < 4; ++i)
            wsu[((n * KS + 144) >> 1) + i] = 0u;
    }
}

// Raw barrier: orders LDS (lgkmcnt) but does NOT drain vmcnt, so global
// prefetch loads issued before it stay in flight across it. sched_barrier
// pins post-barrier ds_reads below the barrier.
#define PIPE_BARRIER() do {                                   \
    asm volatile("s_waitcnt lgkmcnt(0)" ::: "memory");        \
    __builtin_amdgcn_s_barrier();                             \
    __builtin_amdgcn_sched_barrier(0);                        \
} while (0)

__global__ __launch_bounds__(256, 2)
void snn_conv_mfma(const float* __restrict__ in,
                   const uint4v* __restrict__ wsv,   // pre-packed bf16 weights
                   const float* __restrict__ oldp,
                   float* __restrict__ out_spk,
                   float* __restrict__ out_pot)
{
    __shared__ unsigned short s_in[2][YT * XT * PIX_US];        // 2 x 9792 B
    __shared__ alignas(16) unsigned short s_w[CO * KS];         // 19456 B

    const int tid = threadIdx.x;
    const int bx  = blockIdx.x & 15;               // 16 tiles in x
    const int byB = (blockIdx.x >> 4) * NTILES;    // base y-tile (0..124)
    const int tx0 = bx * TX;

    const int lane = tid & 63;
    const int wv   = tid >> 6;       // wave 0..3 -> output row (tile base + wv)
    const int r    = lane & 15;      // pixel-within-16 (B/D) / co-within-16 (A)
    const int quad = lane >> 4;      // 0..3
    const int half = quad & 1;       // ci-half for pixel fragment
    const int tsel = quad >> 1;      // tap parity within K-step

    const int sly  = tid / XT;                 // staging slot coords
    const int slx  = tid - sly * XT;
    const bool sact = tid < YT * XT;           // 204 staging slots

    // ---- stage weights once per block: vector copy of pre-packed bf16
    {
        uint4v* dst = (uint4v*)s_w;
        #pragma unroll
        for (int c = 0; c < 5; ++c) {
            const int idx = tid + c * 256;
            if (idx < SW_CHUNKS) dst[idx] = wsv[idx];
        }
    }

    v4f ra, rb, rc, rd;              // in-flight input slot (one tile)
    bool ivalid;
    f32x4 oldv[2][2][4];             // [parity][mt][nt] double-buffered oldp

    // issue input-slot loads for tile t (regs only; no LDS yet)
    auto issue_in = [&](int t) {
        ivalid = false;
        if (sact) {
            const int gy = (byB + t) * TY + sly - 1;
            const int gx = tx0 + slx - 1;
            if ((unsigned)gy < H && (unsigned)gx < W) {
                const v4f* p = (const v4f*)(in + (gy * W + gx) * CI);
                ra = p[0]; rb = p[1]; rc = p[2]; rd = p[3];
                ivalid = true;
            }
        }
    };

    // pack the in-flight input regs -> s_in[buf]
    auto pack_write = [&](int buf) {
        if (sact) {
            uint4v pk0, pk1;
            if (ivalid) {
                pk0 = (uint4v){pack2bf(ra.x, ra.y), pack2bf(ra.z, ra.w),
                               pack2bf(rb.x, rb.y), pack2bf(rb.z, rb.w)};
                pk1 = (uint4v){pack2bf(rc.x, rc.y), pack2bf(rc.z, rc.w),
                               pack2bf(rd.x, rd.y), pack2bf(rd.z, rd.w)};
            } else {
                pk0 = (uint4v)0u;
                pk1 = (uint4v)0u;
            }
            uint4v* dst = (uint4v*)&s_in[buf][tid * PIX_US];
            dst[0] = pk0;
            dst[1] = pk1;
        }
    };

    // issue oldp loads for tile t into oldv[par]
    auto issue_oldp = [&](int t, int par) {
        #pragma unroll
        for (int mt = 0; mt < 2; ++mt) {
            const int gy = (byB + t) * TY + wv;
            const int gx = tx0 + mt * 16 + r;
            const int eb = (gy * W + gx) * CO + quad * 4;
            #pragma unroll
            for (int nt = 0; nt < 4; ++nt)
                oldv[par][mt][nt] = *(const f32x4*)(oldp + eb + nt * 16);
        }
    };

    auto compute = [&](int buf, f32x4 (&acc)[2][4]) {
        int abase[2];
        #pragma unroll
        for (int mt = 0; mt < 2; ++mt)
            abase[mt] = (wv * XT + mt * 16 + r) * PIX_US + half * 8;
        const short8 zero8 = {0, 0, 0, 0, 0, 0, 0, 0};
        const unsigned short* sb = s_in[buf];

        #pragma unroll
        for (int ks5 = 0; ks5 < 5; ++ks5) {
            const int t0 = ks5 * 2;
            const int t1 = (ks5 == 4) ? 8 : ks5 * 2 + 1;
            const int off0 = ((t0 / 3) * XT + (t0 % 3)) * PIX_US;  // compile-time
            const int off1 = ((t1 / 3) * XT + (t1 % 3)) * PIX_US;  // compile-time
            const int aoff = tsel ? off1 : off0;
            const int koff = (ks5 < 4) ? (ks5 * 32 + quad * 8) : (128 + half * 8);

            short8 bf[4];
            #pragma unroll
            for (int nt = 0; nt < 4; ++nt)
                bf[nt] = *(const short8*)&s_w[(nt * 16 + r) * KS + koff];

            short8 af[2];
            #pragma unroll
            for (int mt = 0; mt < 2; ++mt) {
                short8 a = *(const short8*)&sb[abase[mt] + aoff];
                if (ks5 == 4) a = (quad >= 2) ? zero8 : a;   // zero pad k=144..159
                af[mt] = a;
            }

            // A = weights (M=co), B = pixels (N=pixel); pad zeroed on B side.
            #pragma unroll
            for (int mt = 0; mt < 2; ++mt)
                #pragma unroll
                for (int nt = 0; nt < 4; ++nt)
                    acc[mt][nt] = __builtin_amdgcn_mfma_f32_16x16x32_bf16(
                        bf[nt], af[mt], acc[mt][nt], 0, 0, 0);
        }
    };

    // D layout: col=lane&15 (pixel), row=quad*4+reg (co-within-16) ->
    // each f32x4 acc reg = 4 contiguous co -> dwordx4 stores.
    auto epilogue = [&](int t, int par, f32x4 (&acc)[2][4]) {
        #pragma unroll
        for (int mt = 0; mt < 2; ++mt) {
            const int gy = (byB + t) * TY + wv;
            const int gx = tx0 + mt * 16 + r;
            const int eb = (gy * W + gx) * CO + quad * 4;
            #pragma unroll
            for (int nt = 0; nt < 4; ++nt) {
                const int idx = eb + nt * 16;
                f32x4 np = acc[mt][nt] + oldv[par][mt][nt];
                f32x4 spk, pot;
                #pragma unroll
                for (int j = 0; j < 4; ++j) {
                    const bool s = np[j] >= 1.0f;
                    spk[j] = s ? 1.0f : 0.0f;
                    pot[j] = s ? 0.0f : np[j];
                }
                *(f32x4*)(out_spk + idx) = spk;
                *(f32x4*)(out_pot + idx) = pot;
            }
        }
    };

    // ---- pipeline prologue: tile0 staged, tile1 in flight
    issue_in(0);
    issue_oldp(0, 0);
    pack_write(0);                   // counted vmcnt wait on in(0) only
    issue_in(1);
    issue_oldp(1, 1);
    PIPE_BARRIER();                  // s_w + s_in[0] visible; in(1)/oldp(1) in flight

    // ---- main loop: compute(t) while t+1 packs late & t+2 issues
    #pragma unroll
    for (int i = 0; i < NTILES; ++i) {
        f32x4 acc[2][4] = {};
        compute(i & 1, acc);
        epilogue(i, i & 1, acc);
        if (i < NTILES - 1) {
            pack_write((i + 1) & 1);             // consumes in(i+1)
            if (i < NTILES - 2) {
                issue_in(i + 2);                 // refills in-flight regs
                issue_oldp(i + 2, i & 1);        // reuses parity freed by epilogue(i)
            }
            PIPE_BARRIER();                      // loads for i+2 stay in flight
        }
    }
}

extern "C" void kernel_launch(void* const* d_in, const int* in_sizes, int n_in,
                              void* d_out, int out_size, void* d_ws, size_t ws_size,
                              hipStream_t stream) {
    const float* in   = (const float*)d_in[0];     // (1,512,512,16)
    const float* w    = (const float*)d_in[1];     // (3,3,16,64)
    const float* oldp = (const float*)d_in[2];     // (1,512,512,64)
    float* out_spk = (float*)d_out;
    float* out_pot = out_spk + (size_t)H * W * CO;

    snn_pack_w<<<1, 256, 0, stream>>>(w, (unsigned int*)d_ws);

    const int grid = (W / TX) * (H / (TY * NTILES));   // 512 blocks x 256 thr
    snn_conv_mfma<<<grid, 256, 0, stream>>>(in, (const uint4v*)d_ws, oldp,
                                            out_spk, out_pot);
}